// Round 1
// baseline (572.287 us; speedup 1.0000x reference)
//
#include <hip/hip_runtime.h>
#include <math.h>

#define HW    4096
#define C_CH  2048
#define B_N   8
#define BN_EPS 1e-5f

// ---------------------------------------------------------------------------
// Kernel 1: per-(b,c) mean / max / unbiased std over HW=4096 elements.
// One block per (b,c); 256 threads; each thread loads 4 float4 (16 elems).
// Double accumulation avoids cancellation in sumsq - sum^2/n.
// ---------------------------------------------------------------------------
__global__ __launch_bounds__(256) void stats_kernel(const float* __restrict__ x,
                                                    float* __restrict__ u) {
    const int bc = blockIdx.x;
    const float4* xb = (const float4*)(x + (size_t)bc * HW);
    const int t = threadIdx.x;

    double sum = 0.0, sumsq = 0.0;
    float mx = -INFINITY;
#pragma unroll
    for (int i = 0; i < 4; ++i) {
        float4 v = xb[t + i * 256];
        sum   += (double)v.x + (double)v.y + (double)v.z + (double)v.w;
        sumsq += (double)v.x * v.x + (double)v.y * v.y +
                 (double)v.z * v.z + (double)v.w * v.w;
        mx = fmaxf(mx, fmaxf(fmaxf(v.x, v.y), fmaxf(v.z, v.w)));
    }

    // wave-64 shuffle reduction
#pragma unroll
    for (int off = 32; off > 0; off >>= 1) {
        sum   += __shfl_down(sum, off);
        sumsq += __shfl_down(sumsq, off);
        mx = fmaxf(mx, __shfl_down(mx, off));
    }

    __shared__ double s_sum[4], s_sq[4];
    __shared__ float  s_mx[4];
    const int wave = t >> 6;
    if ((t & 63) == 0) { s_sum[wave] = sum; s_sq[wave] = sumsq; s_mx[wave] = mx; }
    __syncthreads();

    if (t == 0) {
        double S = 0.0, Q = 0.0; float M = -INFINITY;
#pragma unroll
        for (int w = 0; w < 4; ++w) { S += s_sum[w]; Q += s_sq[w]; M = fmaxf(M, s_mx[w]); }
        double mean = S / (double)HW;
        double var  = (Q - S * S / (double)HW) / (double)(HW - 1);
        if (var < 0.0) var = 0.0;
        u[bc * 3 + 0] = (float)mean;
        u[bc * 3 + 1] = M;
        u[bc * 3 + 2] = (float)sqrt(var);
    }
}

// ---------------------------------------------------------------------------
// Kernel 2: per batch b — exact median of u[b] (6144 vals, bitonic sort in
// LDS padded to 8192 with +inf), then gate g[b,c] = sigmoid(BN(conv(u-med)^3)).
// np median of even count = mean of order stats 3071 & 3072.
// ---------------------------------------------------------------------------
__global__ __launch_bounds__(1024) void gate_kernel(const float* __restrict__ u,
                                                    const float* __restrict__ cfc_w,
                                                    const float* __restrict__ bn_w,
                                                    const float* __restrict__ bn_b,
                                                    float* __restrict__ g) {
    __shared__ float s[8192];
    const int b = blockIdx.x, t = threadIdx.x;
    const float* ub = u + (size_t)b * (C_CH * 3);

    for (int i = t; i < 8192; i += 1024)
        s[i] = (i < C_CH * 3) ? ub[i] : INFINITY;

    for (int k = 2; k <= 8192; k <<= 1) {
        for (int j = k >> 1; j > 0; j >>= 1) {
            __syncthreads();
            for (int i = t; i < 8192; i += 1024) {
                const int ixj = i ^ j;
                if (ixj > i) {
                    float a = s[i], c = s[ixj];
                    const bool dir = ((i & k) == 0);   // ascending sub-sequence?
                    if ((a > c) == dir) { s[i] = c; s[ixj] = a; }
                }
            }
        }
    }
    __syncthreads();

    const float med = 0.5f * (s[3071] + s[3072]);
    const float inv = rsqrtf(1.0f + BN_EPS);

    for (int c = t; c < C_CH; c += 1024) {
        float d0 = ub[c * 3 + 0] - med;
        float d1 = ub[c * 3 + 1] - med;
        float d2 = ub[c * 3 + 2] - med;
        float z = d0 * d0 * d0 * cfc_w[c * 3 + 0] +
                  d1 * d1 * d1 * cfc_w[c * 3 + 1] +
                  d2 * d2 * d2 * cfc_w[c * 3 + 2];
        z = z * inv * bn_w[c] + bn_b[c];
        g[b * C_CH + c] = 1.0f / (1.0f + expf(-z));
    }
}

// ---------------------------------------------------------------------------
// Kernel 3: out = x * g[b,c]. One float4 per thread; g index (v>>10) is
// wave-uniform (1024 float4 per channel, 64-aligned).
// ---------------------------------------------------------------------------
__global__ __launch_bounds__(256) void apply_kernel(const float* __restrict__ x,
                                                    const float* __restrict__ g,
                                                    float* __restrict__ out) {
    const size_t v = (size_t)blockIdx.x * 256 + threadIdx.x;  // float4 index
    const float gg = g[v >> 10];                              // 4096/4 per (b,c)
    float4 xv = ((const float4*)x)[v];
    float4 o;
    o.x = xv.x * gg; o.y = xv.y * gg; o.z = xv.z * gg; o.w = xv.w * gg;
    ((float4*)out)[v] = o;
}

extern "C" void kernel_launch(void* const* d_in, const int* in_sizes, int n_in,
                              void* d_out, int out_size, void* d_ws, size_t ws_size,
                              hipStream_t stream) {
    const float* x     = (const float*)d_in[0];
    const float* cfc_w = (const float*)d_in[1];
    const float* bn_w  = (const float*)d_in[2];
    const float* bn_b  = (const float*)d_in[3];
    float* out = (float*)d_out;

    float* u = (float*)d_ws;               // [B, C, 3]  = 49152 floats
    float* g = u + (size_t)B_N * C_CH * 3; // [B, C]     = 16384 floats

    stats_kernel<<<B_N * C_CH, 256, 0, stream>>>(x, u);
    gate_kernel<<<B_N, 1024, 0, stream>>>(u, cfc_w, bn_w, bn_b, g);

    const int total_f4 = (B_N * C_CH * HW) / 4;          // 16,777,216
    apply_kernel<<<total_f4 / 256, 256, 0, stream>>>(x, g, out);
}